// Round 1
// 440.111 us; speedup vs baseline: 1.0780x; 1.0780x over previous
//
#include <hip/hip_runtime.h>

#define DD 768
#define HDIM 96
#define ATT_SCALE 0.10206207261596575f  // 1/sqrt(96)

typedef float floatx4 __attribute__((ext_vector_type(4)));
typedef __bf16 bf16;
typedef bf16 bf16x8 __attribute__((ext_vector_type(8)));
typedef bf16 bf16x4 __attribute__((ext_vector_type(4)));
typedef bf16 bf16x2 __attribute__((ext_vector_type(2)));

__device__ __forceinline__ void gl2lds16(const bf16* g, bf16* l) {
  __builtin_amdgcn_global_load_lds(
      (const __attribute__((address_space(1))) void*)g,
      (__attribute__((address_space(3))) void*)l, 16, 0, 0);
}

// ------------------------------------------------ merged prep kernel
// b<6144: conv_fuse | <7680: f2b(tpe) | <9984: wconv x8 | <10128: wtrans(Wo_s)
__global__ __launch_bounds__(256) void prep(
    const float* __restrict__ features, const float* __restrict__ fpe,
    const float* __restrict__ tpe,
    const float* w0, const float* w1, const float* w2, const float* w3,
    const float* w4, const float* w5, const float* w6, const float* w7,
    bf16* __restrict__ Fb, bf16* __restrict__ Xb, bf16* __restrict__ Feb,
    bf16* __restrict__ Tb, bf16* __restrict__ Wb, bf16* __restrict__ WoT) {
  const int b = blockIdx.x;
  const int tid = threadIdx.x;
  if (b < 6144) {
    const int i = (b * 256 + tid) * 8;
    floatx4 f0 = *(const floatx4*)(features + i);
    floatx4 f1 = *(const floatx4*)(features + i + 4);
    floatx4 e0 = *(const floatx4*)(fpe + i);
    floatx4 e1 = *(const floatx4*)(fpe + i + 4);
    bf16x8 fv, xv, ev;
#pragma unroll
    for (int k = 0; k < 4; k++) {
      fv[k] = (bf16)f0[k];           fv[k + 4] = (bf16)f1[k];
      ev[k] = (bf16)e0[k];           ev[k + 4] = (bf16)e1[k];
      xv[k] = (bf16)(f0[k] + e0[k]); xv[k + 4] = (bf16)(f1[k] + e1[k]);
    }
    *(bf16x8*)(Fb + i) = fv;
    *(bf16x8*)(Xb + i) = xv;
    *(bf16x8*)(Feb + i) = ev;
  } else if (b < 7680) {
    const int i = ((b - 6144) * 256 + tid) * 8;
    floatx4 s0 = *(const floatx4*)(tpe + i);
    floatx4 s1 = *(const floatx4*)(tpe + i + 4);
    bf16x8 v;
#pragma unroll
    for (int k = 0; k < 4; k++) { v[k] = (bf16)s0[k]; v[k + 4] = (bf16)s1[k]; }
    *(bf16x8*)(Tb + i) = v;
  } else if (b < 9984) {
    const int sub = b - 7680;
    const int wi = sub / 288, xb = sub % 288;
    const float* srcs[8] = {w0, w1, w2, w3, w4, w5, w6, w7};
    const float* s = srcs[wi];
    bf16* d = Wb + (size_t)wi * 589824;
    const int i = (xb * 256 + tid) * 8;
    floatx4 s0 = *(const floatx4*)(s + i);
    floatx4 s1 = *(const floatx4*)(s + i + 4);
    bf16x8 v;
#pragma unroll
    for (int k = 0; k < 4; k++) { v[k] = (bf16)s0[k]; v[k + 4] = (bf16)s1[k]; }
    *(bf16x8*)(d + i) = v;
  } else {
    // transpose Wo_s -> WoT bf16
    __shared__ float Ts[64][65];
    const int sub = b - 9984;
    const int X0 = (sub % 12) * 64, Y0 = (sub / 12) * 64;
    const int r = tid >> 2;
    const int c4 = (tid & 3) * 16;
    const float* src = w3 + (size_t)(Y0 + r) * DD + X0 + c4;  // w3 == Wo_s
#pragma unroll
    for (int k = 0; k < 16; k += 4) {
      floatx4 v = *(const floatx4*)(src + k);
      Ts[r][c4 + k] = v[0]; Ts[r][c4 + k + 1] = v[1];
      Ts[r][c4 + k + 2] = v[2]; Ts[r][c4 + k + 3] = v[3];
    }
    __syncthreads();
    bf16 o[16];
#pragma unroll
    for (int k = 0; k < 16; k++) o[k] = (bf16)Ts[c4 + k][r];
    *(bf16x8*)(WoT + (size_t)(X0 + r) * DD + Y0 + c4) = *(bf16x8*)&o[0];
    *(bf16x8*)(WoT + (size_t)(X0 + r) * DD + Y0 + c4 + 8) = *(bf16x8*)&o[8];
  }
}

// ------------------------------------------------ batched LayerNorm (bf16, in place)
__device__ __forceinline__ void ln_row(bf16* x, const float* g, int lane) {
  float v[12], s = 0.f, ss = 0.f;
#pragma unroll
  for (int j = 0; j < 3; j++) {
    bf16x4 b = *(const bf16x4*)&x[j * 256 + lane * 4];
#pragma unroll
    for (int e = 0; e < 4; e++) {
      float t = (float)b[e];
      v[j * 4 + e] = t; s += t; ss += t * t;
    }
  }
#pragma unroll
  for (int o = 32; o > 0; o >>= 1) { s += __shfl_xor(s, o); ss += __shfl_xor(ss, o); }
  const float mean = s * (1.0f / DD);
  const float inv = rsqrtf(ss * (1.0f / DD) - mean * mean + 1e-6f);
#pragma unroll
  for (int j = 0; j < 3; j++) {
    floatx4 gg = *(const floatx4*)&g[j * 256 + lane * 4];
    bf16x4 o4;
#pragma unroll
    for (int e = 0; e < 4; e++) o4[e] = (bf16)((v[j * 4 + e] - mean) * inv * gg[e]);
    *(bf16x4*)&x[j * 256 + lane * 4] = o4;
  }
}

__global__ __launch_bounds__(256) void ln_all(bf16* X0, const float* g0,
                                              bf16* X1, const float* g1,
                                              bf16* X2, const float* g2,
                                              bf16* X3, const float* g3) {
  const int b = blockIdx.x;
  bf16* X; const float* g; int base;
  if (b < 4096)      { X = X0; g = g0; base = b; }
  else if (b < 8192) { X = X1; g = g1; base = b - 4096; }
  else if (b < 9216) { X = X2; g = g2; base = b - 8192; }
  else               { X = X3; g = g3; base = b - 9216; }
  const int w = threadIdx.x >> 6, lane = threadIdx.x & 63;
  ln_row(X + (size_t)(base * 4 + w) * DD, g, lane);
}

// ------------------------------------------------ 256x256 8-phase GEMM core
// 512 threads = 8 waves (2M x 4N), BK=64, 2 K-tiles per iteration, K=768 fixed.
// LDS 128 KiB: A tiles [0,16384)+[16384,32768) elems, B at +32768 same split.
// T2 XOR swizzle: LDS[r][slot] holds global k-slot (slot ^ (r&7)); ds_read uses
// slot ^ (fr&7). Staging keeps linear LDS dest (global_load_lds) + pre-swizzled
// global source (rule #21). Counted vmcnt(4) at phases 4/8 only (T3+T4),
// s_setprio around MFMA clusters (T5).
#define BAR() do { __builtin_amdgcn_sched_barrier(0); \
                   __builtin_amdgcn_s_barrier(); \
                   __builtin_amdgcn_sched_barrier(0); } while (0)
#define VMW(n) asm volatile("s_waitcnt vmcnt(" #n ")" ::: "memory")

template <int MODE>
__device__ __forceinline__ void gemm256(const bf16* __restrict__ A,
                                        const bf16* __restrict__ W,
                                        bf16* __restrict__ Cb,
                                        float* __restrict__ Cf,
                                        const float* __restrict__ addsrc,
                                        bf16* lds, int row0, int col0) {
  const int tid = threadIdx.x;           // 0..511
  const int lane = tid & 63;
  const int w = tid >> 6;                // 0..7
  const int wm = (w & 1) * 128;          // WARPS_M = 2
  const int wn = (w >> 1) * 64;          // WARPS_N = 4
  const int fr = lane & 15;
  const int quad = lane >> 4;
  const int f7 = fr & 7;

  // staging: thread covers global row (tid>>3), 16B slot (tid&7), swizzled src
  const int srow = tid >> 3;
  const int sswz = ((tid & 7) ^ (srow & 7)) * 8;
  const bf16* Ag = A + (size_t)(row0 + srow) * DD + sswz;
  const bf16* Wg = W + (size_t)(col0 + srow) * DD + sswz;
  bf16* dA = lds + tid * 8;              // linear DMA dest (wave base + lane*16B)
  bf16* dB = lds + 32768 + tid * 8;

#define STGA(tau, h) do { \
    gl2lds16(Ag + (size_t)((h) * 128) * DD + (tau) * 64, \
             dA + ((tau) & 1) * 16384 + (h) * 8192); \
    gl2lds16(Ag + (size_t)((h) * 128 + 64) * DD + (tau) * 64, \
             dA + ((tau) & 1) * 16384 + (h) * 8192 + 4096); \
  } while (0)
#define STGB(tau, h) do { \
    gl2lds16(Wg + (size_t)((h) * 128) * DD + (tau) * 64, \
             dB + ((tau) & 1) * 16384 + (h) * 8192); \
    gl2lds16(Wg + (size_t)((h) * 128 + 64) * DD + (tau) * 64, \
             dB + ((tau) & 1) * 16384 + (h) * 8192 + 4096); \
  } while (0)

  // swizzled ds_read element offsets for k-slot (ks*4+quad)
  const int sl0 = (quad ^ f7) * 8;
  const int sl1 = ((4 | quad) ^ f7) * 8;

#define LDA8(buf, mh) do { \
    _Pragma("unroll") for (int m = 0; m < 4; m++) { \
      const bf16* p = lds + (buf) * 16384 + (wm + (mh) * 64 + m * 16 + fr) * 64; \
      af[m][0] = *(const bf16x8*)(p + sl0); \
      af[m][1] = *(const bf16x8*)(p + sl1); } \
  } while (0)
#define LDB4(buf, nh, dst) do { \
    _Pragma("unroll") for (int n = 0; n < 2; n++) { \
      const bf16* p = lds + 32768 + (buf) * 16384 + (wn + (nh) * 32 + n * 16 + fr) * 64; \
      dst[n][0] = *(const bf16x8*)(p + sl0); \
      dst[n][1] = *(const bf16x8*)(p + sl1); } \
  } while (0)
#define MM16(mh, nbase, bb) do { \
    __builtin_amdgcn_s_setprio(1); \
    _Pragma("unroll") for (int m = 0; m < 4; m++) \
    _Pragma("unroll") for (int n = 0; n < 2; n++) { \
      acc[(mh) * 4 + m][(nbase) + n] = __builtin_amdgcn_mfma_f32_16x16x32_bf16( \
          af[m][0], bb[n][0], acc[(mh) * 4 + m][(nbase) + n], 0, 0, 0); \
      acc[(mh) * 4 + m][(nbase) + n] = __builtin_amdgcn_mfma_f32_16x16x32_bf16( \
          af[m][1], bb[n][1], acc[(mh) * 4 + m][(nbase) + n], 0, 0, 0); } \
    __builtin_amdgcn_s_setprio(0); \
  } while (0)

  floatx4 acc[8][4];

  // prologue: tile0 fully + tile1 B halves; vmcnt(4) -> tile0 landed
  STGB(0, 0); STGB(0, 1); STGA(0, 0); STGA(0, 1);
  STGB(1, 0); STGB(1, 1);
#pragma unroll
  for (int i = 0; i < 8; i++)
#pragma unroll
    for (int j = 0; j < 4; j++) acc[i][j] = (floatx4){0, 0, 0, 0};
  VMW(4);
  BAR();

  bf16x8 af[4][2], b0[2][2], b1[2][2];

  for (int it = 0; it < 6; ++it) {
    const int a = 2 * it;
    const bool stg = (it < 5);
    // ph1: buf0 A-low + B n0/1; stage (a+1).Alo -> buf1.A (free since prev ph7)
    LDA8(0, 0); LDB4(0, 0, b0);
    STGA(a + 1, 0);
    BAR();
    MM16(0, 0, b0);
    BAR();
    // ph2: B n2/3; stage (a+1).Ahi
    LDB4(0, 1, b1);
    STGA(a + 1, 1);
    BAR();
    MM16(0, 2, b1);
    BAR();
    // ph3: A-high; stage (a+2).Blo -> buf0.B (free after ph2)
    LDA8(0, 1);
    if (stg) STGB(a + 2, 0);
    BAR();
    MM16(1, 2, b1);
    BAR();
    // ph4: reuse b0; stage (a+2).Bhi; counted vmcnt -> (a+1) fully landed
    if (stg) STGB(a + 2, 1);
    BAR();
    MM16(1, 0, b0);
    if (stg) { VMW(4); } else { VMW(0); }
    BAR();
    // ph5: buf1 tile a+1; stage (a+2).Alo -> buf0.A (free after ph3)
    LDA8(1, 0); LDB4(1, 0, b0);
    if (stg) STGA(a + 2, 0);
    BAR();
    MM16(0, 0, b0);
    BAR();
    // ph6
    LDB4(1, 1, b1);
    if (stg) STGA(a + 2, 1);
    BAR();
    MM16(0, 2, b1);
    BAR();
    // ph7: stage (a+3).Blo -> buf1.B (free after ph6)
    LDA8(1, 1);
    if (stg) STGB(a + 3, 0);
    BAR();
    MM16(1, 2, b1);
    BAR();
    // ph8: counted vmcnt -> (a+2) fully landed for next ph1
    if (stg) STGB(a + 3, 1);
    BAR();
    MM16(1, 0, b0);
    if (stg) VMW(4);
    BAR();
  }

#pragma unroll
  for (int m = 0; m < 8; m++)
#pragma unroll
    for (int n = 0; n < 4; n++)
#pragma unroll
      for (int r = 0; r < 4; r++) {
        const int row = row0 + wm + m * 16 + quad * 4 + r;
        const int col = col0 + wn + n * 16 + fr;
        const size_t idx = (size_t)row * DD + col;
        if (MODE == 0) Cb[idx] = (bf16)acc[m][n][r];
        else Cf[idx] = acc[m][n][r] + addsrc[idx];
      }
#undef STGA
#undef STGB
#undef LDA8
#undef LDB4
#undef MM16
}

// one launch: z=0..2 big GEMMs; z=3: x<16 Qs, x<32 K2, x<35 Wcr, else idle
__global__ __launch_bounds__(512, 2) void gemm_all(
    const bf16* Xb, const bf16* Fb, const bf16* Feb, const bf16* Tb,
    const bf16* Wb, const bf16* WoT,
    bf16* Kc, bf16* Vc, bf16* Qb2, bf16* Qc, bf16* K2, bf16* Wcr) {
  __shared__ bf16 lds[65536];
  const size_t SW = (size_t)768 * 768;
  const int z = blockIdx.z;
  if (z == 0)
    gemm256<0>(Xb, Wb + 1 * SW, Kc, nullptr, nullptr, lds,
               blockIdx.x * 256, blockIdx.y * 256);
  else if (z == 1)
    gemm256<0>(Fb, Wb + 2 * SW, Vc, nullptr, nullptr, lds,
               blockIdx.x * 256, blockIdx.y * 256);
  else if (z == 2)
    gemm256<0>(Feb, Wb + 4 * SW, Qb2, nullptr, nullptr, lds,
               blockIdx.x * 256, blockIdx.y * 256);
  else {
    const int x = blockIdx.x;
    if (x < 16)
      gemm256<0>(Tb, Wb + 0 * SW, Qc, nullptr, nullptr, lds,
                 x * 256, blockIdx.y * 256);
    else if (x < 32)
      gemm256<0>(Tb, Wb + 5 * SW, K2, nullptr, nullptr, lds,
                 (x - 16) * 256, blockIdx.y * 256);
    else if (x < 35)
      gemm256<0>(Wb + 6 * SW, WoT, Wcr, nullptr, nullptr, lds,
                 (x - 32) * 256, blockIdx.y * 256);
  }
}

__global__ __launch_bounds__(512, 2) void gemm_b(const bf16* A, const bf16* W, bf16* C) {
  __shared__ bf16 lds[65536];
  gemm256<0>(A, W, C, nullptr, nullptr, lds, blockIdx.x * 256, blockIdx.y * 256);
}

__global__ __launch_bounds__(512, 2) void gemm_final(const bf16* A, const bf16* W,
                                                     float* C, const float* addsrc) {
  __shared__ bf16 lds[65536];
  gemm256<1>(A, W, nullptr, C, addsrc, lds, blockIdx.x * 256, blockIdx.y * 256);
}

// ------------------------------------------------ fused attention, 512 threads
// 2 query-groups of 64 rows share one K/V stage. No-max softmax (scores bounded).
// SPLIT: write unnormalized O partial (bf16) + l per row. grid b = (sp*npq+qt)*128 + t*8 + h.
template <int SPLIT>
__global__ __launch_bounds__(512, 4) void attn512(
    const bf16* __restrict__ Qb, const bf16* __restrict__ Kb,
    const bf16* __restrict__ Vb, bf16* __restrict__ Ob,
    float* __restrict__ Ml,
    const float* __restrict__ qpos, int qpos_ts,
    const float* __restrict__ kpos, int kpos_ts,
    int nq, int nk, int npq, int nsp) {
  const int b = blockIdx.x;
  const int h = b & 7;
  const int t = (b >> 3) & 15;
  const int rest = b >> 7;
  const int qt = rest % npq;
  const int sp = rest / npq;
  const int klen = nk / nsp;
  const int k0s = sp * klen;
  const int q0 = qt * 128;
  const bf16* Q = Qb + (size_t)t * nq * DD + h * HDIM;
  const bf16* K = Kb + (size_t)t * nk * DD + h * HDIM;
  const bf16* V = Vb + (size_t)t * nk * DD + h * HDIM;
  bf16* O = Ob + (size_t)(SPLIT ? (sp * 16 + t) : t) * nq * DD + h * HDIM;
  const float* qp = qpos + (size_t)t * qpos_ts;
  const float* kp = kpos + (size_t)t * kpos_ts;

  __shared__ bf16 Ks[64 * 104];       // [n][k] stride 104
  __shared__ bf16 Vt[96 * 72];        // [d][n] stride 72
  __shared__ bf16 Ps[2 * 64 * 72];    // per-group [m][n]

  const int tid = threadIdx.x;
  const int w = tid >> 6;
  const int g = w >> 2;
  const int wl = w & 3;
  const int lane = tid & 63;
  const int fr = lane & 15;
  const int quad = lane >> 4;
  const int rowb = wl * 16;
  const int qgb = q0 + g * 64;
  bf16* Pg = &Ps[g * 64 * 72];

  bf16x8 qf[3];
  {
    const bf16* qrow = Q + (size_t)(qgb + rowb + fr) * DD;
#pragma unroll
    for (int c = 0; c < 3; c++) qf[c] = *(const bf16x8*)(qrow + c * 32 + quad * 8);
  }
  float qx[4], qy[4];
#pragma unroll
  for (int r = 0; r < 4; r++) {
    int qi = qgb + rowb + quad * 4 + r;
    qx[r] = qp[qi * 2];
    qy[r] = qp[qi * 2 + 1];
  }

  float lrow[4] = {0.f, 0.f, 0.f, 0.f};
  floatx4 oacc[6];
#pragma unroll
  for (int d = 0; d < 6; d++) oacc[d] = (floatx4){0, 0, 0, 0};

  const int krA = tid >> 3, kcA = (tid & 7) * 8;
  const int krB = (tid & 255) >> 2, kcB = 64 + (tid & 3) * 8;
  const int nb = (tid & 31) * 2, db = (tid >> 5) * 6;

  for (int n0 = k0s; n0 < k0s + klen; n0 += 64) {
    __syncthreads();
    *(bf16x8*)&Ks[krA * 104 + kcA] =
        *(const bf16x8*)(K + (size_t)(n0 + krA) * DD + kcA);
    if (tid < 256)
      *(bf16x8*)&Ks[krB * 104 + kcB] =
          *(const bf16x8*)(K + (size_t)(n0 + krB) * DD + kcB);
    {
      bf16 tmp[2][6];
#pragma unroll
      for (int nn = 0; nn < 2; nn++) {
        const unsigned* vg = (const unsigned*)(V + (size_t)(n0 + nb + nn) * DD + db);
        unsigned u0 = vg[0], u1 = vg[1], u2 = vg[2];
        *(unsigned*)&tmp[nn][0] = u0;
        *(unsigned*)&tmp[nn][2] = u1;
        *(unsigned*)&tmp[nn][4] = u2;
      }
#pragma unroll
      for (int dd = 0; dd < 6; dd++) {
        bf16x2 v2 = {tmp[0][dd], tmp[1][dd]};
        *(bf16x2*)&Vt[(db + dd) * 72 + nb] = v2;
      }
    }
    __syncthreads();

    floatx4 s4[4];
#pragma unroll
    for (int j = 0; j < 4; j++) {
      floatx4 sa = {0, 0, 0, 0};
#pragma unroll
      for (int c = 0; c < 3; c++) {
        bf16x8 kf = *(const bf16x8*)&Ks[(j * 16 + fr) * 104 + c * 32 + quad * 8];
        sa = __builtin_amdgcn_mfma_f32_16x16x32_bf16(qf[c], kf, sa, 0, 0, 0);
      }
      s4[j] = sa;
    }
    float kxx[4], kyy[4];
#pragma unroll
    for (int j = 0; j < 4; j++) {
      int ki = (n0 + j * 16 + fr) * 2;
      kxx[j] = kp[ki];
      kyy[j] = kp[ki + 1];
    }
#pragma unroll
    for (int j = 0; j < 4; j++)
#pragma unroll
      for (int r = 0; r < 4; r++) {
        float dx = qx[r] - kxx[j], dy = qy[r] - kyy[j];
        float sv = s4[j][r] * ATT_SCALE - 2.0f * (dx * dx + dy * dy);
        float pv = __expf(sv);
        lrow[r] += pv;
        Pg[(rowb + quad * 4 + r) * 72 + j * 16 + fr] = (bf16)pv;
      }
    bf16x8 pf0 = *(const bf16x8*)&Pg[(rowb + fr) * 72 + quad * 8];
    bf16x8 pf1 = *(const bf16x8*)&Pg[(rowb + fr) * 72 + 32 + quad * 8];
#pragma unroll
    for (int d = 0; d < 6; d++) {
      bf16x8 v0 = *(const bf16x8*)&Vt[(d * 16 + fr) * 72 + quad * 8];
      bf16x8 v1 = *(const bf16x8*)&Vt[(d * 16 + fr) * 72 + 32 + quad * 8];
      oacc[d] = __builtin_amdgcn_mfma_f32_16x16x32_bf16(pf0, v0, oacc[d], 0, 0, 0);
      oacc[d] = __builtin_amdgcn_mfma_f32_16x16x32_bf16(pf1, v1, oacc[d], 0, 0, 0);
    }
  }

#pragma unroll
  for (int r = 0; r < 4; r++)
#pragma unroll
    for (int o = 1; o < 16; o <<= 1) lrow[r] += __shfl_xor(lrow[r], o);

#pragma unroll
  for (int r = 0; r < 4; r++) {
    int row = qgb + rowb + quad * 4 + r;
    if (SPLIT) {
#pragma unroll
      for (int d = 0; d < 6; d++)
        O[(size_t)row * DD + d * 16 + fr] = (bf16)oacc[d][r];
      if (fr == 0)
        Ml[((size_t)(sp * 16 + t) * 8 + h) * nq + row] = lrow[r];
    } else {
      float inv = 1.0f / lrow[r];
#pragma unroll
      for (int d = 0; d < 6; d++)
        O[(size_t)row * DD + d * 16 + fr] = (bf16)(oacc[d][r] * inv);
    }
  }
}

// combine 4 unnormalized split partials: Out = (ΣO_s) / (Σl_s)
__global__ __launch_bounds__(256) void combine4(const bf16* __restrict__ Op,
                                                const float* __restrict__ Ml,
                                                bf16* __restrict__ Out) {
  const int row = blockIdx.x;  // t*256 + q
  const int t = row >> 8;
  const int q = row & 255;
#pragma unroll
  for (int e = 0; e < 3; e++) {
    int dim = threadIdx.x + e * 256;
    int hh = dim / 96;
    float osum = 0.f, lsum = 0.f;
#pragma unroll
    for (int s = 0; s < 4; s++) {
      lsum += Ml[((size_t)(s * 16 + t) * 8 + hh) * 256 + q];
      osum += (float)Op[((size_t)(s * 16 + t) * 256 + q) * DD + dim];
    }
    Out[(size_t)row * DD + dim] = (bf16)(osum / lsum);
  }
}

// ------------------------------------------------ launch
extern "C" void kernel_launch(void* const* d_in, const int* in_sizes, int n_in,
                              void* d_out, int out_size, void* d_ws, size_t ws_size,
                              hipStream_t stream) {
  const float* features = (const float*)d_in[0];
  const float* tracks   = (const float*)d_in[1];
  const float* fpos     = (const float*)d_in[2];
  const float* tpe      = (const float*)d_in[3];
  const float* fpe      = (const float*)d_in[4];
  const float* Wq_s     = (const float*)d_in[5];
  const float* Wk_s     = (const float*)d_in[6];
  const float* Wv_s     = (const float*)d_in[7];
  const float* qg_s     = (const float*)d_in[8];
  const float* kg_s     = (const float*)d_in[9];
  const float* Wo_s     = (const float*)d_in[10];
  const float* Wq_p     = (const float*)d_in[11];
  const float* Wk_p     = (const float*)d_in[12];
  const float* Wv_p     = (const float*)d_in[13];
  const float* qg_p     = (const float*)d_in[14];
  const float* kg_p     = (const float*)d_in[15];
  const float* Wout_p   = (const float*)d_in[16];
  float* out = (float*)d_out;

  const size_t SB = (size_t)16 * 1024 * 768;
  const size_t SS = (size_t)16 * 256 * 768;
  const size_t SW = (size_t)768 * 768;
  bf16* p = (bf16*)d_ws;
  bf16* Fb  = p; p += SB;     // features bf16 (reused as U)
  bf16* Xb  = p; p += SB;     // features+fpe
  bf16* Feb = p; p += SB;     // fpe bf16
  bf16* Kc  = p; p += SB;     // K_s
  bf16* Vc  = p; p += SB;     // V_s
  bf16* Qb2 = p; p += SB;     // Q2
  bf16* Tb  = p; p += SS;     // tpe bf16
  bf16* Qc  = p; p += SS;     // Q_s (reused as V2)
  bf16* K2  = p; p += SS;     // K2
  bf16* Sh  = p; p += SS;     // sampled heads
  bf16* Op  = p; p += 4 * SS; // split-K partial O
  bf16* Wb  = p; p += 8 * SW; // weights bf16
  bf16* WoT = p; p += SW;     // Wo_s^T
  bf16* Wcr = p; p += SW;     // Wv_p @ Wo_s
  float* Ml = (float*)p;      // split-K l
  bf16* V2 = Qc; bf16* U = Fb;

  dim3 blk(256);

  prep<<<10128, blk, 0, stream>>>(features, fpe, tpe,
                                  Wq_s, Wk_s, Wv_s, Wo_s, Wq_p, Wk_p, Wv_p, Wout_p,
                                  Fb, Xb, Feb, Tb, Wb, WoT);
  gemm_all<<<dim3(64, 3, 4), dim3(512), 0, stream>>>(Xb, Fb, Feb, Tb, Wb, WoT,
                                                     Kc, Vc, Qb2, Qc, K2, Wcr);
  ln_all<<<10240, blk, 0, stream>>>(Kc, kg_s, Qb2, qg_p, Qc, qg_s, K2, kg_p);
  attn512<1><<<1024, dim3(512), 0, stream>>>(Qc, Kc, Vc, Op, Ml,
                                             tracks, 512, fpos, 0, 256, 1024, 2, 4);
  combine4<<<4096, blk, 0, stream>>>(Op, Ml, Sh);
  gemm_b<<<dim3(16, 3), dim3(512), 0, stream>>>(Sh, Wcr, V2);
  attn512<0><<<1024, dim3(512), 0, stream>>>(Qb2, K2, V2, U, nullptr,
                                             fpos, 0, tracks, 512, 1024, 256, 8, 1);
  gemm_final<<<dim3(64, 3), dim3(512), 0, stream>>>(U, Wb + 7 * SW, out, features);
}

// Round 2
// 436.486 us; speedup vs baseline: 1.0869x; 1.0083x over previous
//
#include <hip/hip_runtime.h>

#define DD 768
#define HDIM 96
#define ATT_SCALE 0.10206207261596575f  // 1/sqrt(96)

typedef float floatx4 __attribute__((ext_vector_type(4)));
typedef __bf16 bf16;
typedef bf16 bf16x8 __attribute__((ext_vector_type(8)));
typedef bf16 bf16x4 __attribute__((ext_vector_type(4)));
typedef bf16 bf16x2 __attribute__((ext_vector_type(2)));

__device__ __forceinline__ void gl2lds16(const bf16* g, bf16* l) {
  __builtin_amdgcn_global_load_lds(
      (const __attribute__((address_space(1))) void*)g,
      (__attribute__((address_space(3))) void*)l, 16, 0, 0);
}

// ------------------------------------------------ merged prep kernel
// b<6144: conv_fuse | <7680: f2b(tpe) | <9984: wconv x8 | <10128: wtrans(Wo_s)
__global__ __launch_bounds__(256) void prep(
    const float* __restrict__ features, const float* __restrict__ fpe,
    const float* __restrict__ tpe,
    const float* w0, const float* w1, const float* w2, const float* w3,
    const float* w4, const float* w5, const float* w6, const float* w7,
    bf16* __restrict__ Fb, bf16* __restrict__ Xb, bf16* __restrict__ Feb,
    bf16* __restrict__ Tb, bf16* __restrict__ Wb, bf16* __restrict__ WoT) {
  const int b = blockIdx.x;
  const int tid = threadIdx.x;
  if (b < 6144) {
    const int i = (b * 256 + tid) * 8;
    floatx4 f0 = *(const floatx4*)(features + i);
    floatx4 f1 = *(const floatx4*)(features + i + 4);
    floatx4 e0 = *(const floatx4*)(fpe + i);
    floatx4 e1 = *(const floatx4*)(fpe + i + 4);
    bf16x8 fv, xv, ev;
#pragma unroll
    for (int k = 0; k < 4; k++) {
      fv[k] = (bf16)f0[k];           fv[k + 4] = (bf16)f1[k];
      ev[k] = (bf16)e0[k];           ev[k + 4] = (bf16)e1[k];
      xv[k] = (bf16)(f0[k] + e0[k]); xv[k + 4] = (bf16)(f1[k] + e1[k]);
    }
    *(bf16x8*)(Fb + i) = fv;
    *(bf16x8*)(Xb + i) = xv;
    *(bf16x8*)(Feb + i) = ev;
  } else if (b < 7680) {
    const int i = ((b - 6144) * 256 + tid) * 8;
    floatx4 s0 = *(const floatx4*)(tpe + i);
    floatx4 s1 = *(const floatx4*)(tpe + i + 4);
    bf16x8 v;
#pragma unroll
    for (int k = 0; k < 4; k++) { v[k] = (bf16)s0[k]; v[k + 4] = (bf16)s1[k]; }
    *(bf16x8*)(Tb + i) = v;
  } else if (b < 9984) {
    const int sub = b - 7680;
    const int wi = sub / 288, xb = sub % 288;
    const float* srcs[8] = {w0, w1, w2, w3, w4, w5, w6, w7};
    const float* s = srcs[wi];
    bf16* d = Wb + (size_t)wi * 589824;
    const int i = (xb * 256 + tid) * 8;
    floatx4 s0 = *(const floatx4*)(s + i);
    floatx4 s1 = *(const floatx4*)(s + i + 4);
    bf16x8 v;
#pragma unroll
    for (int k = 0; k < 4; k++) { v[k] = (bf16)s0[k]; v[k + 4] = (bf16)s1[k]; }
    *(bf16x8*)(d + i) = v;
  } else {
    // transpose Wo_s -> WoT bf16
    __shared__ float Ts[64][65];
    const int sub = b - 9984;
    const int X0 = (sub % 12) * 64, Y0 = (sub / 12) * 64;
    const int r = tid >> 2;
    const int c4 = (tid & 3) * 16;
    const float* src = w3 + (size_t)(Y0 + r) * DD + X0 + c4;  // w3 == Wo_s
#pragma unroll
    for (int k = 0; k < 16; k += 4) {
      floatx4 v = *(const floatx4*)(src + k);
      Ts[r][c4 + k] = v[0]; Ts[r][c4 + k + 1] = v[1];
      Ts[r][c4 + k + 2] = v[2]; Ts[r][c4 + k + 3] = v[3];
    }
    __syncthreads();
    bf16 o[16];
#pragma unroll
    for (int k = 0; k < 16; k++) o[k] = (bf16)Ts[c4 + k][r];
    *(bf16x8*)(WoT + (size_t)(X0 + r) * DD + Y0 + c4) = *(bf16x8*)&o[0];
    *(bf16x8*)(WoT + (size_t)(X0 + r) * DD + Y0 + c4 + 8) = *(bf16x8*)&o[8];
  }
}

// ------------------------------------------------ batched LayerNorm (bf16, in place)
__device__ __forceinline__ void ln_row(bf16* x, const float* g, int lane) {
  float v[12], s = 0.f, ss = 0.f;
#pragma unroll
  for (int j = 0; j < 3; j++) {
    bf16x4 b = *(const bf16x4*)&x[j * 256 + lane * 4];
#pragma unroll
    for (int e = 0; e < 4; e++) {
      float t = (float)b[e];
      v[j * 4 + e] = t; s += t; ss += t * t;
    }
  }
#pragma unroll
  for (int o = 32; o > 0; o >>= 1) { s += __shfl_xor(s, o); ss += __shfl_xor(ss, o); }
  const float mean = s * (1.0f / DD);
  const float inv = rsqrtf(ss * (1.0f / DD) - mean * mean + 1e-6f);
#pragma unroll
  for (int j = 0; j < 3; j++) {
    floatx4 gg = *(const floatx4*)&g[j * 256 + lane * 4];
    bf16x4 o4;
#pragma unroll
    for (int e = 0; e < 4; e++) o4[e] = (bf16)((v[j * 4 + e] - mean) * inv * gg[e]);
    *(bf16x4*)&x[j * 256 + lane * 4] = o4;
  }
}

__global__ __launch_bounds__(256) void ln_all(bf16* X0, const float* g0,
                                              bf16* X1, const float* g1,
                                              bf16* X2, const float* g2,
                                              bf16* X3, const float* g3) {
  const int b = blockIdx.x;
  bf16* X; const float* g; int base;
  if (b < 4096)      { X = X0; g = g0; base = b; }
  else if (b < 8192) { X = X1; g = g1; base = b - 4096; }
  else if (b < 9216) { X = X2; g = g2; base = b - 8192; }
  else               { X = X3; g = g3; base = b - 9216; }
  const int w = threadIdx.x >> 6, lane = threadIdx.x & 63;
  ln_row(X + (size_t)(base * 4 + w) * DD, g, lane);
}

// ------------------------------------------------ 256x256 8-phase GEMM core
// 512 threads = 8 waves (2M x 4N), BK=64, 2 K-tiles per iteration, K=768 fixed.
// T2 XOR swizzle + T3/T4 counted vmcnt + T5 setprio (verified r1: 0 bank conf).
#define BAR() do { __builtin_amdgcn_sched_barrier(0); \
                   __builtin_amdgcn_s_barrier(); \
                   __builtin_amdgcn_sched_barrier(0); } while (0)
#define VMW(n) asm volatile("s_waitcnt vmcnt(" #n ")" ::: "memory")

template <int MODE>
__device__ __forceinline__ void gemm256(const bf16* __restrict__ A,
                                        const bf16* __restrict__ W,
                                        bf16* __restrict__ Cb,
                                        float* __restrict__ Cf,
                                        const float* __restrict__ addsrc,
                                        bf16* lds, int row0, int col0) {
  const int tid = threadIdx.x;           // 0..511
  const int lane = tid & 63;
  const int w = tid >> 6;                // 0..7
  const int wm = (w & 1) * 128;          // WARPS_M = 2
  const int wn = (w >> 1) * 64;          // WARPS_N = 4
  const int fr = lane & 15;
  const int quad = lane >> 4;
  const int f7 = fr & 7;

  const int srow = tid >> 3;
  const int sswz = ((tid & 7) ^ (srow & 7)) * 8;
  const bf16* Ag = A + (size_t)(row0 + srow) * DD + sswz;
  const bf16* Wg = W + (size_t)(col0 + srow) * DD + sswz;
  bf16* dA = lds + tid * 8;
  bf16* dB = lds + 32768 + tid * 8;

#define STGA(tau, h) do { \
    gl2lds16(Ag + (size_t)((h) * 128) * DD + (tau) * 64, \
             dA + ((tau) & 1) * 16384 + (h) * 8192); \
    gl2lds16(Ag + (size_t)((h) * 128 + 64) * DD + (tau) * 64, \
             dA + ((tau) & 1) * 16384 + (h) * 8192 + 4096); \
  } while (0)
#define STGB(tau, h) do { \
    gl2lds16(Wg + (size_t)((h) * 128) * DD + (tau) * 64, \
             dB + ((tau) & 1) * 16384 + (h) * 8192); \
    gl2lds16(Wg + (size_t)((h) * 128 + 64) * DD + (tau) * 64, \
             dB + ((tau) & 1) * 16384 + (h) * 8192 + 4096); \
  } while (0)

  const int sl0 = (quad ^ f7) * 8;
  const int sl1 = ((4 | quad) ^ f7) * 8;

#define LDA8(buf, mh) do { \
    _Pragma("unroll") for (int m = 0; m < 4; m++) { \
      const bf16* p = lds + (buf) * 16384 + (wm + (mh) * 64 + m * 16 + fr) * 64; \
      af[m][0] = *(const bf16x8*)(p + sl0); \
      af[m][1] = *(const bf16x8*)(p + sl1); } \
  } while (0)
#define LDB4(buf, nh, dst) do { \
    _Pragma("unroll") for (int n = 0; n < 2; n++) { \
      const bf16* p = lds + 32768 + (buf) * 16384 + (wn + (nh) * 32 + n * 16 + fr) * 64; \
      dst[n][0] = *(const bf16x8*)(p + sl0); \
      dst[n][1] = *(const bf16x8*)(p + sl1); } \
  } while (0)
#define MM16(mh, nbase, bb) do { \
    __builtin_amdgcn_s_setprio(1); \
    _Pragma("unroll") for (int m = 0; m < 4; m++) \
    _Pragma("unroll") for (int n = 0; n < 2; n++) { \
      acc[(mh) * 4 + m][(nbase) + n] = __builtin_amdgcn_mfma_f32_16x16x32_bf16( \
          af[m][0], bb[n][0], acc[(mh) * 4 + m][(nbase) + n], 0, 0, 0); \
      acc[(mh) * 4 + m][(nbase) + n] = __builtin_amdgcn_mfma_f32_16x16x32_bf16( \
          af[m][1], bb[n][1], acc[(mh) * 4 + m][(nbase) + n], 0, 0, 0); } \
    __builtin_amdgcn_s_setprio(0); \
  } while (0)

  floatx4 acc[8][4];

  STGB(0, 0); STGB(0, 1); STGA(0, 0); STGA(0, 1);
  STGB(1, 0); STGB(1, 1);
#pragma unroll
  for (int i = 0; i < 8; i++)
#pragma unroll
    for (int j = 0; j < 4; j++) acc[i][j] = (floatx4){0, 0, 0, 0};
  VMW(4);
  BAR();

  bf16x8 af[4][2], b0[2][2], b1[2][2];

  for (int it = 0; it < 6; ++it) {
    const int a = 2 * it;
    const bool stg = (it < 5);
    LDA8(0, 0); LDB4(0, 0, b0);
    STGA(a + 1, 0);
    BAR();
    MM16(0, 0, b0);
    BAR();
    LDB4(0, 1, b1);
    STGA(a + 1, 1);
    BAR();
    MM16(0, 2, b1);
    BAR();
    LDA8(0, 1);
    if (stg) STGB(a + 2, 0);
    BAR();
    MM16(1, 2, b1);
    BAR();
    if (stg) STGB(a + 2, 1);
    BAR();
    MM16(1, 0, b0);
    if (stg) { VMW(4); } else { VMW(0); }
    BAR();
    LDA8(1, 0); LDB4(1, 0, b0);
    if (stg) STGA(a + 2, 0);
    BAR();
    MM16(0, 0, b0);
    BAR();
    LDB4(1, 1, b1);
    if (stg) STGA(a + 2, 1);
    BAR();
    MM16(0, 2, b1);
    BAR();
    LDA8(1, 1);
    if (stg) STGB(a + 3, 0);
    BAR();
    MM16(1, 2, b1);
    BAR();
    if (stg) STGB(a + 3, 1);
    BAR();
    MM16(1, 0, b0);
    if (stg) VMW(4);
    BAR();
  }

#pragma unroll
  for (int m = 0; m < 8; m++)
#pragma unroll
    for (int n = 0; n < 4; n++)
#pragma unroll
      for (int r = 0; r < 4; r++) {
        const int row = row0 + wm + m * 16 + quad * 4 + r;
        const int col = col0 + wn + n * 16 + fr;
        const size_t idx = (size_t)row * DD + col;
        if (MODE == 0) Cb[idx] = (bf16)acc[m][n][r];
        else Cf[idx] = acc[m][n][r] + addsrc[idx];
      }
#undef STGA
#undef STGB
#undef LDA8
#undef LDB4
#undef MM16
}

// one launch: z=0..2 big GEMMs; z=3: x<16 Qs, x<32 K2, x<35 Wcr, else idle
__global__ __launch_bounds__(512, 2) void gemm_all(
    const bf16* Xb, const bf16* Fb, const bf16* Feb, const bf16* Tb,
    const bf16* Wb, const bf16* WoT,
    bf16* Kc, bf16* Vc, bf16* Qb2, bf16* Qc, bf16* K2, bf16* Wcr) {
  __shared__ bf16 lds[65536];
  const size_t SW = (size_t)768 * 768;
  const int z = blockIdx.z;
  if (z == 0)
    gemm256<0>(Xb, Wb + 1 * SW, Kc, nullptr, nullptr, lds,
               blockIdx.x * 256, blockIdx.y * 256);
  else if (z == 1)
    gemm256<0>(Fb, Wb + 2 * SW, Vc, nullptr, nullptr, lds,
               blockIdx.x * 256, blockIdx.y * 256);
  else if (z == 2)
    gemm256<0>(Feb, Wb + 4 * SW, Qb2, nullptr, nullptr, lds,
               blockIdx.x * 256, blockIdx.y * 256);
  else {
    const int x = blockIdx.x;
    if (x < 16)
      gemm256<0>(Tb, Wb + 0 * SW, Qc, nullptr, nullptr, lds,
                 x * 256, blockIdx.y * 256);
    else if (x < 32)
      gemm256<0>(Tb, Wb + 5 * SW, K2, nullptr, nullptr, lds,
                 (x - 16) * 256, blockIdx.y * 256);
    else if (x < 35)
      gemm256<0>(Wb + 6 * SW, WoT, Wcr, nullptr, nullptr, lds,
                 (x - 32) * 256, blockIdx.y * 256);
  }
}

__global__ __launch_bounds__(512, 2) void gemm_b(const bf16* A, const bf16* W, bf16* C) {
  __shared__ bf16 lds[65536];
  gemm256<0>(A, W, C, nullptr, nullptr, lds, blockIdx.x * 256, blockIdx.y * 256);
}

__global__ __launch_bounds__(512, 2) void gemm_final(const bf16* A, const bf16* W,
                                                     float* C, const float* addsrc) {
  __shared__ bf16 lds[65536];
  gemm256<1>(A, W, nullptr, C, addsrc, lds, blockIdx.x * 256, blockIdx.y * 256);
}

// ------------------------------------------------ fused attention, 512 threads
// 2 query-groups of 64 rows share one K/V stage. No-max softmax (scores bounded).
// T14 async-STAGE: tile i+1's K/V prefetched into regs (A/B named sets) during
// tile i's compute; ds_write after barrier. kp staged once per block into LDS.
// SPLIT: write unnormalized O partial (bf16) + l per row.
template <int SPLIT>
__global__ __launch_bounds__(512, 4) void attn512(
    const bf16* __restrict__ Qb, const bf16* __restrict__ Kb,
    const bf16* __restrict__ Vb, bf16* __restrict__ Ob,
    float* __restrict__ Ml,
    const float* __restrict__ qpos, int qpos_ts,
    const float* __restrict__ kpos, int kpos_ts,
    int nq, int nk, int npq, int nsp) {
  const int b = blockIdx.x;
  const int h = b & 7;
  const int t = (b >> 3) & 15;
  const int rest = b >> 7;
  const int qt = rest % npq;
  const int sp = rest / npq;
  const int klen = nk / nsp;   // == 256 at both call sites
  const int k0s = sp * klen;
  const int q0 = qt * 128;
  const bf16* Q = Qb + (size_t)t * nq * DD + h * HDIM;
  const bf16* K = Kb + (size_t)t * nk * DD + h * HDIM;
  const bf16* V = Vb + (size_t)t * nk * DD + h * HDIM;
  bf16* O = Ob + (size_t)(SPLIT ? (sp * 16 + t) : t) * nq * DD + h * HDIM;
  const float* qp = qpos + (size_t)t * qpos_ts;
  const float* kp = kpos + (size_t)t * kpos_ts;

  __shared__ bf16 Ks[64 * 104];       // [n][k] stride 104
  __shared__ bf16 Vt[96 * 72];        // [d][n] stride 72
  __shared__ bf16 Ps[2 * 64 * 72];    // per-group [m][n]
  __shared__ float Kpl[512];          // key positions for this block's klen

  const int tid = threadIdx.x;
  const int w = tid >> 6;
  const int g = w >> 2;
  const int wl = w & 3;
  const int lane = tid & 63;
  const int fr = lane & 15;
  const int quad = lane >> 4;
  const int rowb = wl * 16;
  const int qgb = q0 + g * 64;
  bf16* Pg = &Ps[g * 64 * 72];

  bf16x8 qf[3];
  {
    const bf16* qrow = Q + (size_t)(qgb + rowb + fr) * DD;
#pragma unroll
    for (int c = 0; c < 3; c++) qf[c] = *(const bf16x8*)(qrow + c * 32 + quad * 8);
  }
  float qx[4], qy[4];
#pragma unroll
  for (int r = 0; r < 4; r++) {
    int qi = qgb + rowb + quad * 4 + r;
    qx[r] = qp[qi * 2];
    qy[r] = qp[qi * 2 + 1];
  }

  float lrow[4] = {0.f, 0.f, 0.f, 0.f};
  floatx4 oacc[6];
#pragma unroll
  for (int d = 0; d < 6; d++) oacc[d] = (floatx4){0, 0, 0, 0};

  const int krA = tid >> 3, kcA = (tid & 7) * 8;
  const int krB = (tid & 255) >> 2, kcB = 64 + (tid & 3) * 8;
  const int nb = (tid & 31) * 2, db = (tid >> 5) * 6;

  // key positions -> LDS (coalesced, once per block)
  Kpl[tid] = kp[(size_t)k0s * 2 + tid];

  struct VR { unsigned a, b, c; };
  bf16x8 kaA, kbA, kaB, kbB;
  VR vA0, vA1, vB0, vB1;

  auto loadreg = [&](int n0, bf16x8& ka, bf16x8& kb, VR& r0, VR& r1) {
    ka = *(const bf16x8*)(K + (size_t)(n0 + krA) * DD + kcA);
    if (tid < 256) kb = *(const bf16x8*)(K + (size_t)(n0 + krB) * DD + kcB);
    const unsigned* g0 = (const unsigned*)(V + (size_t)(n0 + nb) * DD + db);
    const unsigned* g1 = (const unsigned*)(V + (size_t)(n0 + nb + 1) * DD + db);
    r0.a = g0[0]; r0.b = g0[1]; r0.c = g0[2];
    r1.a = g1[0]; r1.b = g1[1]; r1.c = g1[2];
  };
  auto writelds = [&](const bf16x8& ka, const bf16x8& kb, const VR& r0, const VR& r1) {
    *(bf16x8*)&Ks[krA * 104 + kcA] = ka;
    if (tid < 256) *(bf16x8*)&Ks[krB * 104 + kcB] = kb;
    bf16 t0[6], t1[6];
    *(unsigned*)&t0[0] = r0.a; *(unsigned*)&t0[2] = r0.b; *(unsigned*)&t0[4] = r0.c;
    *(unsigned*)&t1[0] = r1.a; *(unsigned*)&t1[2] = r1.b; *(unsigned*)&t1[4] = r1.c;
#pragma unroll
    for (int dd = 0; dd < 6; dd++) {
      bf16x2 v2 = {t0[dd], t1[dd]};
      *(bf16x2*)&Vt[(db + dd) * 72 + nb] = v2;
    }
  };
  auto compute = [&](int rel) {  // rel = n0 - k0s
    floatx4 s4[4];
#pragma unroll
    for (int j = 0; j < 4; j++) {
      floatx4 sa = {0, 0, 0, 0};
#pragma unroll
      for (int c = 0; c < 3; c++) {
        bf16x8 kf = *(const bf16x8*)&Ks[(j * 16 + fr) * 104 + c * 32 + quad * 8];
        sa = __builtin_amdgcn_mfma_f32_16x16x32_bf16(qf[c], kf, sa, 0, 0, 0);
      }
      s4[j] = sa;
    }
    float kxx[4], kyy[4];
#pragma unroll
    for (int j = 0; j < 4; j++) {
      int ki = (rel + j * 16 + fr) * 2;
      kxx[j] = Kpl[ki];
      kyy[j] = Kpl[ki + 1];
    }
#pragma unroll
    for (int j = 0; j < 4; j++)
#pragma unroll
      for (int r = 0; r < 4; r++) {
        float dx = qx[r] - kxx[j], dy = qy[r] - kyy[j];
        float sv = s4[j][r] * ATT_SCALE - 2.0f * (dx * dx + dy * dy);
        float pv = __expf(sv);
        lrow[r] += pv;
        Pg[(rowb + quad * 4 + r) * 72 + j * 16 + fr] = (bf16)pv;
      }
    bf16x8 pf0 = *(const bf16x8*)&Pg[(rowb + fr) * 72 + quad * 8];
    bf16x8 pf1 = *(const bf16x8*)&Pg[(rowb + fr) * 72 + 32 + quad * 8];
#pragma unroll
    for (int d = 0; d < 6; d++) {
      bf16x8 v0 = *(const bf16x8*)&Vt[(d * 16 + fr) * 72 + quad * 8];
      bf16x8 v1 = *(const bf16x8*)&Vt[(d * 16 + fr) * 72 + 32 + quad * 8];
      oacc[d] = __builtin_amdgcn_mfma_f32_16x16x32_bf16(pf0, v0, oacc[d], 0, 0, 0);
      oacc[d] = __builtin_amdgcn_mfma_f32_16x16x32_bf16(pf1, v1, oacc[d], 0, 0, 0);
    }
  };

  const int NT = klen >> 6;  // tiles of 64 keys (== 4 at both call sites)
  loadreg(k0s, kaA, kbA, vA0, vA1);
  for (int n = 0; n < NT; n += 2) {
    __syncthreads();
    writelds(kaA, kbA, vA0, vA1);
    if (n + 1 < NT) loadreg(k0s + (n + 1) * 64, kaB, kbB, vB0, vB1);
    __syncthreads();
    compute(n * 64);
    if (n + 1 >= NT) break;
    __syncthreads();
    writelds(kaB, kbB, vB0, vB1);
    if (n + 2 < NT) loadreg(k0s + (n + 2) * 64, kaA, kbA, vA0, vA1);
    __syncthreads();
    compute((n + 1) * 64);
  }

#pragma unroll
  for (int r = 0; r < 4; r++)
#pragma unroll
    for (int o = 1; o < 16; o <<= 1) lrow[r] += __shfl_xor(lrow[r], o);

#pragma unroll
  for (int r = 0; r < 4; r++) {
    int row = qgb + rowb + quad * 4 + r;
    if (SPLIT) {
#pragma unroll
      for (int d = 0; d < 6; d++)
        O[(size_t)row * DD + d * 16 + fr] = (bf16)oacc[d][r];
      if (fr == 0)
        Ml[((size_t)(sp * 16 + t) * 8 + h) * nq + row] = lrow[r];
    } else {
      float inv = 1.0f / lrow[r];
#pragma unroll
      for (int d = 0; d < 6; d++)
        O[(size_t)row * DD + d * 16 + fr] = (bf16)(oacc[d][r] * inv);
    }
  }
}

// combine 4 unnormalized split partials: Out = (ΣO_s) / (Σl_s)
__global__ __launch_bounds__(256) void combine4(const bf16* __restrict__ Op,
                                                const float* __restrict__ Ml,
                                                bf16* __restrict__ Out) {
  const int row = blockIdx.x;  // t*256 + q
  const int t = row >> 8;
  const int q = row & 255;
#pragma unroll
  for (int e = 0; e < 3; e++) {
    int dim = threadIdx.x + e * 256;
    int hh = dim / 96;
    float osum = 0.f, lsum = 0.f;
#pragma unroll
    for (int s = 0; s < 4; s++) {
      lsum += Ml[((size_t)(s * 16 + t) * 8 + hh) * 256 + q];
      osum += (float)Op[((size_t)(s * 16 + t) * 256 + q) * DD + dim];
    }
    Out[(size_t)row * DD + dim] = (bf16)(osum / lsum);
  }
}

// ------------------------------------------------ launch
extern "C" void kernel_launch(void* const* d_in, const int* in_sizes, int n_in,
                              void* d_out, int out_size, void* d_ws, size_t ws_size,
                              hipStream_t stream) {
  const float* features = (const float*)d_in[0];
  const float* tracks   = (const float*)d_in[1];
  const float* fpos     = (const float*)d_in[2];
  const float* tpe      = (const float*)d_in[3];
  const float* fpe      = (const float*)d_in[4];
  const float* Wq_s     = (const float*)d_in[5];
  const float* Wk_s     = (const float*)d_in[6];
  const float* Wv_s     = (const float*)d_in[7];
  const float* qg_s     = (const float*)d_in[8];
  const float* kg_s     = (const float*)d_in[9];
  const float* Wo_s     = (const float*)d_in[10];
  const float* Wq_p     = (const float*)d_in[11];
  const float* Wk_p     = (const float*)d_in[12];
  const float* Wv_p     = (const float*)d_in[13];
  const float* qg_p     = (const float*)d_in[14];
  const float* kg_p     = (const float*)d_in[15];
  const float* Wout_p   = (const float*)d_in[16];
  float* out = (float*)d_out;

  const size_t SB = (size_t)16 * 1024 * 768;
  const size_t SS = (size_t)16 * 256 * 768;
  const size_t SW = (size_t)768 * 768;
  bf16* p = (bf16*)d_ws;
  bf16* Fb  = p; p += SB;     // features bf16 (reused as U)
  bf16* Xb  = p; p += SB;     // features+fpe
  bf16* Feb = p; p += SB;     // fpe bf16
  bf16* Kc  = p; p += SB;     // K_s
  bf16* Vc  = p; p += SB;     // V_s
  bf16* Qb2 = p; p += SB;     // Q2
  bf16* Tb  = p; p += SS;     // tpe bf16
  bf16* Qc  = p; p += SS;     // Q_s (reused as V2)
  bf16* K2  = p; p += SS;     // K2
  bf16* Sh  = p; p += SS;     // sampled heads
  bf16* Op  = p; p += 4 * SS; // split-K partial O
  bf16* Wb  = p; p += 8 * SW; // weights bf16
  bf16* WoT = p; p += SW;     // Wo_s^T
  bf16* Wcr = p; p += SW;     // Wv_p @ Wo_s
  float* Ml = (float*)p;      // split-K l
  bf16* V2 = Qc; bf16* U = Fb;

  dim3 blk(256);

  prep<<<10128, blk, 0, stream>>>(features, fpe, tpe,
                                  Wq_s, Wk_s, Wv_s, Wo_s, Wq_p, Wk_p, Wv_p, Wout_p,
                                  Fb, Xb, Feb, Tb, Wb, WoT);
  gemm_all<<<dim3(64, 3, 4), dim3(512), 0, stream>>>(Xb, Fb, Feb, Tb, Wb, WoT,
                                                     Kc, Vc, Qb2, Qc, K2, Wcr);
  ln_all<<<10240, blk, 0, stream>>>(Kc, kg_s, Qb2, qg_p, Qc, qg_s, K2, kg_p);
  attn512<1><<<1024, dim3(512), 0, stream>>>(Qc, Kc, Vc, Op, Ml,
                                             tracks, 512, fpos, 0, 256, 1024, 2, 4);
  combine4<<<4096, blk, 0, stream>>>(Op, Ml, Sh);
  gemm_b<<<dim3(16, 3), dim3(512), 0, stream>>>(Sh, Wcr, V2);
  attn512<0><<<1024, dim3(512), 0, stream>>>(Qb2, K2, V2, U, nullptr,
                                             fpos, 0, tracks, 512, 1024, 256, 8, 1);
  gemm_final<<<dim3(64, 3), dim3(512), 0, stream>>>(U, Wb + 7 * SW, out, features);
}